// Round 1
// baseline (397.908 us; speedup 1.0000x reference)
//
#include <hip/hip_runtime.h>
#include <cstdint>
#include <cstddef>

// Problem constants
#define NN   4096   // N
#define FIN  512    // F_IN
#define FOUT 256    // F_OUT
// C = 4, channel-last everywhere -> float4 per (..) element

typedef short bf16x8 __attribute__((ext_vector_type(8)));
typedef float f32x4  __attribute__((ext_vector_type(4)));

__device__ __forceinline__ unsigned short f2bf(float f) {
    union { float f; unsigned u; } v; v.f = f;
    unsigned r = v.u + 0x7FFFu + ((v.u >> 16) & 1u);   // RNE
    return (unsigned short)(r >> 16);
}

// ---------------------------------------------------------------------------
// Kernel 0: Wsum_T[r][j] = sum_c weight[j][r][c]   (bf16, [256][512] K-major)
// ---------------------------------------------------------------------------
__global__ __launch_bounds__(256) void k_prep_wsum(const float4* __restrict__ w4,
                                                   unsigned short* __restrict__ wsumT) {
    int t = blockIdx.x * 256 + threadIdx.x;   // 0 .. 131071
    int r = t & (FOUT - 1);
    int j = t >> 8;
    float4 v = w4[j * FOUT + r];              // coalesced across r
    wsumT[r * FIN + j] = f2bf(v.x + v.y + v.z + v.w);
}

// ---------------------------------------------------------------------------
// GEMM template: 16 rows x 256 cols per block, 512 threads (8 waves),
// BK=64, bf16 MFMA 16x16x32, A staged via LDS, A+B prefetched 1 chunk ahead.
// MODE 0: A = x (fp32, row stride 512). Epilogue: write H_T bf16 [256][4096].
// MODE 1: A = sum_c adjs (float4 per elem, row stride 4096).
//         Epilogue: out[i][r][c] = dot + bias[i][r][c] (float4 per (i,r)).
// ---------------------------------------------------------------------------
template<int K, int MODE>
__global__ __launch_bounds__(512) void k_gemm16(
    const void* __restrict__ Aptr,
    const unsigned short* __restrict__ Bt,   // [256][K] bf16, K-major
    unsigned short* __restrict__ Ht,         // MODE 0 output
    const float4* __restrict__ bias4,        // MODE 1
    float4* __restrict__ out4)               // MODE 1
{
    constexpr int NCHUNK = K / 64;
    __shared__ unsigned short Abf[16 * 72];  // 16 rows x 64 bf16, pad to 72

    const int tid  = threadIdx.x;
    const int lane = tid & 63;
    const int wave = tid >> 6;         // 0..7
    const int quad = lane >> 4;        // 0..3
    const int l15  = lane & 15;
    const int i0   = blockIdx.x * 16;

    // staging assignment: row si (0..15), col pair sk (0,2,..,62)
    const int si = tid >> 5;
    const int sk = (tid & 31) * 2;

    f32x4 acc0 = {0.f, 0.f, 0.f, 0.f};
    f32x4 acc1 = {0.f, 0.f, 0.f, 0.f};

    float4 pa0, pa1;                   // A prefetch (MODE1: 2 x float4; MODE0: pa0.x/.y)
    bf16x8 bp00, bp01, bp10, bp11;     // B prefetch

    auto loadA = [&](int c) {
        const int j0 = c * 64;
        if (MODE == 0) {
            const float* xp = (const float*)Aptr;
            const float2 t2 = *(const float2*)(xp + (size_t)(i0 + si) * FIN + j0 + sk);
            pa0.x = t2.x; pa0.y = t2.y;
        } else {
            const float4* ap = (const float4*)Aptr;
            size_t base = (size_t)(i0 + si) * NN + j0 + sk;
            pa0 = ap[base];
            pa1 = ap[base + 1];
        }
    };
    auto loadB = [&](int c, bf16x8& b00, bf16x8& b01, bf16x8& b10, bf16x8& b11) {
        const int j0 = c * 64;
        const unsigned short* p0 = Bt + (size_t)(wave * 32 + l15) * K + j0 + quad * 8;
        b00 = *(const bf16x8*)(p0);
        b01 = *(const bf16x8*)(p0 + 32);
        const unsigned short* p1 = p0 + (size_t)16 * K;
        b10 = *(const bf16x8*)(p1);
        b11 = *(const bf16x8*)(p1 + 32);
    };

    loadA(0);
    loadB(0, bp00, bp01, bp10, bp11);

    for (int c = 0; c < NCHUNK; ++c) {
        __syncthreads();   // previous chunk's LDS reads complete
        if (MODE == 0) {
            unsigned pack = (unsigned)f2bf(pa0.x) | ((unsigned)f2bf(pa0.y) << 16);
            *(unsigned*)&Abf[si * 72 + sk] = pack;
        } else {
            float s0 = (pa0.x + pa0.y) + (pa0.z + pa0.w);
            float s1 = (pa1.x + pa1.y) + (pa1.z + pa1.w);
            *(unsigned*)&Abf[si * 72 + sk] =
                (unsigned)f2bf(s0) | ((unsigned)f2bf(s1) << 16);
        }
        __syncthreads();   // LDS visible

        // rotate B prefetch into current
        bf16x8 bc00 = bp00, bc01 = bp01, bc10 = bp10, bc11 = bp11;
        if (c + 1 < NCHUNK) {
            loadA(c + 1);                               // overlaps MFMA below
            loadB(c + 1, bp00, bp01, bp10, bp11);
        }

        bf16x8 a0 = *(const bf16x8*)&Abf[l15 * 72 + quad * 8];
        bf16x8 a1 = *(const bf16x8*)&Abf[l15 * 72 + 32 + quad * 8];

        acc0 = __builtin_amdgcn_mfma_f32_16x16x32_bf16(a0, bc00, acc0, 0, 0, 0);
        acc0 = __builtin_amdgcn_mfma_f32_16x16x32_bf16(a1, bc01, acc0, 0, 0, 0);
        acc1 = __builtin_amdgcn_mfma_f32_16x16x32_bf16(a0, bc10, acc1, 0, 0, 0);
        acc1 = __builtin_amdgcn_mfma_f32_16x16x32_bf16(a1, bc11, acc1, 0, 0, 0);
    }

    // Epilogue. D layout: col = lane&15, row = quad*4 + reg  (m89-verified)
    if (MODE == 0) {
        const int n  = wave * 32 + l15;
        const int ib = i0 + quad * 4;
        ushort4 h;
        h.x = f2bf(acc0[0]); h.y = f2bf(acc0[1]); h.z = f2bf(acc0[2]); h.w = f2bf(acc0[3]);
        *(ushort4*)(Ht + (size_t)n * NN + ib) = h;
        h.x = f2bf(acc1[0]); h.y = f2bf(acc1[1]); h.z = f2bf(acc1[2]); h.w = f2bf(acc1[3]);
        *(ushort4*)(Ht + (size_t)(n + 16) * NN + ib) = h;
    } else {
        const int col = wave * 32 + l15;
        const int ib  = i0 + quad * 4;
#pragma unroll
        for (int r = 0; r < 4; ++r) {
            size_t idx = (size_t)(ib + r) * FOUT + col;
            float4 bv = bias4[idx];
            float  s  = acc0[r];
            float4 o; o.x = s + bv.x; o.y = s + bv.y; o.z = s + bv.z; o.w = s + bv.w;
            out4[idx] = o;
            float4 bv1 = bias4[idx + 16];
            float  s1  = acc1[r];
            float4 o1; o1.x = s1 + bv1.x; o1.y = s1 + bv1.y; o1.z = s1 + bv1.z; o1.w = s1 + bv1.w;
            out4[idx + 16] = o1;
        }
    }
}

// ---------------------------------------------------------------------------
extern "C" void kernel_launch(void* const* d_in, const int* in_sizes, int n_in,
                              void* d_out, int out_size, void* d_ws, size_t ws_size,
                              hipStream_t stream) {
    const float*  x     = (const float*)d_in[0];   // [4096][512] f32
    const float4* adjs4 = (const float4*)d_in[1];  // [4096][4096] x float4 (C=4)
    const float4* w4    = (const float4*)d_in[2];  // [512][256] x float4
    const float4* bias4 = (const float4*)d_in[3];  // [4096][256] x float4
    float4*       out4  = (float4*)d_out;          // [4096][256] x float4

    unsigned short* wsumT = (unsigned short*)d_ws;                       // 256*512 bf16 (256 KiB)
    unsigned short* Ht    = (unsigned short*)((char*)d_ws + (size_t)FOUT * FIN * 2); // 256*4096 bf16 (2 MiB)

    // Wsum^T (bf16, K-major)
    k_prep_wsum<<<(FIN * FOUT) / 256, 256, 0, stream>>>(w4, wsumT);
    // H^T = (x @ Wsum)^T  (bf16, [256][4096])
    k_gemm16<FIN, 0><<<NN / 16, 512, 0, stream>>>((const void*)x, wsumT, Ht, nullptr, nullptr);
    // out = Asum @ H + bias
    k_gemm16<NN, 1><<<NN / 16, 512, 0, stream>>>((const void*)adjs4, Ht, nullptr, bias4, out4);
}